// Round 3
// baseline (40129.938 us; speedup 1.0000x reference)
//
#include <hip/hip_runtime.h>

// CapsNet forward, fp32, batch-chunked.
// Per-chunk ws layout (floats):
//   [0, C*9216)                u (reduced conv2 out, caps layout)
//   [C*9216, C*193536)         region A:
//        h1       at +0        (C*102400)   conv1 out
//        partials at +C*102400 (4*C*9216)   conv2 split-K partials (disjoint from h1)
//        uhat     at +0        (C*184320)   overwrites h1+partials after both dead

// ---------------- conv1 + ReLU: [C,1,28,28] -> [C,256,20,20] ----------------
__global__ __launch_bounds__(320) void conv1_k(const float* __restrict__ in,
                                               const float* __restrict__ w,
                                               const float* __restrict__ bias,
                                               float* __restrict__ h1) {
    int blk = blockIdx.x;
    int b = blk >> 4;
    int c0 = (blk & 15) * 16;
    __shared__ float img[784];
    __shared__ float wl[16 * 81];
    __shared__ float bl[16];
    int tid = threadIdx.x;
    for (int t = tid; t < 784; t += 320) img[t] = in[b * 784 + t];
    for (int t = tid; t < 1296; t += 320) wl[t] = w[c0 * 81 + t];
    if (tid < 16) bl[tid] = bias[c0 + tid];
    __syncthreads();

    int co = tid / 20, oy = tid % 20;
    float wr[81];
#pragma unroll
    for (int k = 0; k < 81; k++) wr[k] = wl[co * 81 + k];
    float acc[20];
    float bv = bl[co];
#pragma unroll
    for (int ox = 0; ox < 20; ox++) acc[ox] = bv;

#pragma unroll
    for (int ky = 0; ky < 9; ky++) {
        const float* rp = &img[(oy + ky) * 28];
        float r[28];
#pragma unroll
        for (int v = 0; v < 7; v++) {
            float4 t4 = ((const float4*)rp)[v];
            r[v * 4 + 0] = t4.x; r[v * 4 + 1] = t4.y;
            r[v * 4 + 2] = t4.z; r[v * 4 + 3] = t4.w;
        }
#pragma unroll
        for (int kx = 0; kx < 9; kx++) {
            float wv = wr[ky * 9 + kx];
#pragma unroll
            for (int ox = 0; ox < 20; ox++) acc[ox] += r[ox + kx] * wv;
        }
    }
    float* op = &h1[(b * 256 + c0 + co) * 400 + oy * 20];
#pragma unroll
    for (int v = 0; v < 5; v++) {
        float4 s4;
        s4.x = fmaxf(acc[v * 4 + 0], 0.f);
        s4.y = fmaxf(acc[v * 4 + 1], 0.f);
        s4.z = fmaxf(acc[v * 4 + 2], 0.f);
        s4.w = fmaxf(acc[v * 4 + 3], 0.f);
        ((float4*)op)[v] = s4;
    }
}

// ---------------- conv2 split-4: each block = (b, 64-channel quarter) ----------------
// grid 4C blocks, 256 threads (one per c_out). Partials: part[s][b][9216].
__global__ __launch_bounds__(256, 4) void conv2_k(const float* __restrict__ h1,
                                                  const float* __restrict__ w,
                                                  float* __restrict__ part, int C) {
    int b = blockIdx.x >> 2;
    int s = blockIdx.x & 3;
    int co = threadIdx.x;
    __shared__ float tile[8 * 400];
    float acc[36];
#pragma unroll
    for (int k = 0; k < 36; k++) acc[k] = 0.f;

    const float* wp = &w[co * 20736 + s * 64 * 81];

    for (int ct = 0; ct < 8; ct++) {
        __syncthreads();
        const float4* src = (const float4*)&h1[(b * 256 + s * 64 + ct * 8) * 400];
        for (int t = threadIdx.x; t < 800; t += 256) ((float4*)tile)[t] = src[t];
        __syncthreads();

#pragma unroll 1
        for (int cc = 0; cc < 8; cc++) {
            const float* wq = &wp[(ct * 8 + cc) * 81];
            float wr[81];
#pragma unroll
            for (int k = 0; k < 81; k++) wr[k] = wq[k];
            const float* ip = &tile[cc * 400];
#pragma unroll
            for (int y = 0; y < 19; y++) {
                float r[20];
#pragma unroll
                for (int v = 0; v < 5; v++) {
                    float4 t4 = ((const float4*)&ip[y * 20])[v];
                    r[v * 4 + 0] = t4.x; r[v * 4 + 1] = t4.y;
                    r[v * 4 + 2] = t4.z; r[v * 4 + 3] = t4.w;
                }
#pragma unroll
                for (int oy = 0; oy < 6; oy++) {
                    int ky = y - 2 * oy;
                    if (ky >= 0 && ky < 9) {
#pragma unroll
                        for (int kx = 0; kx < 9; kx++) {
                            float wv = wr[ky * 9 + kx];
#pragma unroll
                            for (int ox = 0; ox < 6; ox++)
                                acc[oy * 6 + ox] += r[2 * ox + kx] * wv;
                        }
                    }
                }
            }
        }
    }
    float* pp = &part[((size_t)s * C + b) * 9216];
#pragma unroll
    for (int oy = 0; oy < 6; oy++)
#pragma unroll
        for (int ox = 0; ox < 6; ox++)
            pp[ox * 1536 + oy * 256 + co] = acc[oy * 6 + ox];
}

// ---------------- reduce 4 partials + bias -> u ----------------
// grid C*9 blocks, 256 threads; one float4 per thread.
__global__ __launch_bounds__(256) void reduce_k(const float* __restrict__ part,
                                                const float* __restrict__ bias,
                                                float* __restrict__ u, int C) {
    int n = (blockIdx.x * 256 + threadIdx.x) * 4;
    size_t stride = (size_t)C * 9216;
    float4 a0 = *(const float4*)&part[n];
    float4 a1 = *(const float4*)&part[stride + n];
    float4 a2 = *(const float4*)&part[2 * stride + n];
    float4 a3 = *(const float4*)&part[3 * stride + n];
    float4 bv = *(const float4*)&bias[n & 255];
    float4 r;
    r.x = a0.x + a1.x + a2.x + a3.x + bv.x;
    r.y = a0.y + a1.y + a2.y + a3.y + bv.y;
    r.z = a0.z + a1.z + a2.z + a3.z + bv.z;
    r.w = a0.w + a1.w + a2.w + a3.w + bv.w;
    *(float4*)&u[n] = r;
}

// ---------------- u_hat: u[b,i,p] x W[i,j,p,q] -> uhat[b][j*16+q][i] ----------------
__global__ __launch_bounds__(256) void uhat_k(const float* __restrict__ u,
                                              const float* __restrict__ W,
                                              float* __restrict__ uhat) {
    int i0 = blockIdx.x * 64;
    int b0 = blockIdx.y * 8;
    __shared__ float ul[8 * 64 * 9];
    __shared__ float wl[64 * 129];
    int tid = threadIdx.x;

    for (int t = tid; t < 4096; t += 256) {
        int bb = t >> 9, r = t & 511;
        ul[bb * 576 + (r >> 3) * 9 + (r & 7)] = u[(b0 + bb) * 9216 + i0 * 8 + r];
    }

    int il = tid & 63, g = tid >> 6;
    for (int j = 0; j < 10; j++) {
        __syncthreads();
        for (int t = tid; t < 2048; t += 256) {
            int li = t >> 5, off = (t & 31) * 4;
            float4 v = *(const float4*)&W[(i0 + li) * 1280 + j * 128 + off];
            float* d = &wl[li * 129 + off];
            d[0] = v.x; d[1] = v.y; d[2] = v.z; d[3] = v.w;
        }
        __syncthreads();
#pragma unroll 1
        for (int bb = 0; bb < 8; bb++) {
            float ur[8];
#pragma unroll
            for (int p = 0; p < 8; p++) ur[p] = ul[bb * 576 + il * 9 + p];
#pragma unroll
            for (int k = 0; k < 4; k++) {
                int q = g * 4 + k;
                float a = 0.f;
#pragma unroll
                for (int p = 0; p < 8; p++) a += ur[p] * wl[il * 129 + p * 16 + q];
                uhat[((b0 + bb) * 160 + j * 16 + q) * 1152 + i0 + il] = a;
            }
        }
    }
}

// ---------------- dynamic routing (3 iters) -> out[C,10,16] ----------------
__global__ __launch_bounds__(256) void route_k(const float* __restrict__ uhat,
                                               float* __restrict__ out) {
    int b = blockIdx.x;
    int tid = threadIdx.x;
    __shared__ float c_lds[1152 * 10];
    __shared__ float s_lds[160];
    __shared__ float v_lds[160];
    const float* base = uhat + (size_t)b * 160 * 1152;

    float breg[5][10];
#pragma unroll
    for (int ch = 0; ch < 5; ch++)
#pragma unroll
        for (int j = 0; j < 10; j++) breg[ch][j] = 0.f;

    int wave = tid >> 6, lane = tid & 63;

    for (int t = 0; t < 3; t++) {
        // ---- phase A: coupling coefficients c ----
        if (t == 0) {
            for (int k = tid; k < 11520; k += 256) c_lds[k] = 0.1f;
        } else {
#pragma unroll
            for (int ch = 0; ch < 5; ch++) {
                int i = ch * 256 + tid;
                if (i < 1152) {
#pragma unroll
                    for (int j = 0; j < 10; j++) {
                        float d = 0.f;
#pragma unroll
                        for (int q = 0; q < 16; q++)
                            d += base[(j * 16 + q) * 1152 + i] * v_lds[j * 16 + q];
                        breg[ch][j] += d;
                    }
                    float m = breg[ch][0];
#pragma unroll
                    for (int j = 1; j < 10; j++) m = fmaxf(m, breg[ch][j]);
                    float e[10];
                    float sum = 0.f;
#pragma unroll
                    for (int j = 0; j < 10; j++) { e[j] = __expf(breg[ch][j] - m); sum += e[j]; }
                    float inv = 1.0f / sum;
#pragma unroll
                    for (int j = 0; j < 10; j++) c_lds[i * 10 + j] = e[j] * inv;
                }
            }
        }
        __syncthreads();
        // ---- phase B: s_jq = sum_i c_ij * uhat_ijq  (wave-per-jq, coalesced) ----
        for (int jq = wave; jq < 160; jq += 4) {
            int j = jq >> 4;
            const float* up = base + (size_t)jq * 1152;
            float s = 0.f;
#pragma unroll 2
            for (int k = 0; k < 18; k++) {
                int i = lane + k * 64;
                s += up[i] * c_lds[i * 10 + j];
            }
#pragma unroll
            for (int off = 32; off; off >>= 1) s += __shfl_down(s, off);
            if (lane == 0) s_lds[jq] = s;
        }
        __syncthreads();
        // ---- squash ----
        if (tid < 10) {
            float sq = 0.f;
#pragma unroll
            for (int q = 0; q < 16; q++) { float x = s_lds[tid * 16 + q]; sq += x * x; }
            float norm = sqrtf(sq + 1e-8f);
            float scale = (sq / (1.0f + sq)) / norm;
#pragma unroll
            for (int q = 0; q < 16; q++) v_lds[tid * 16 + q] = s_lds[tid * 16 + q] * scale;
        }
        __syncthreads();
    }
    if (tid < 160) out[b * 160 + tid] = v_lds[tid];
}

extern "C" void kernel_launch(void* const* d_in, const int* in_sizes, int n_in,
                              void* d_out, int out_size, void* d_ws, size_t ws_size,
                              hipStream_t stream) {
    const float* input = (const float*)d_in[0];
    const float* c1w = (const float*)d_in[1];
    const float* c1b = (const float*)d_in[2];
    const float* c2w = (const float*)d_in[3];
    const float* c2b = (const float*)d_in[4];
    const float* capW = (const float*)d_in[5];
    float* out = (float*)d_out;
    float* ws = (float*)d_ws;

    int C = 0;
    const int cands[7] = {512, 256, 128, 64, 32, 16, 8};
    for (int k = 0; k < 7; k++) {
        size_t need = (size_t)cands[k] * 193536 * sizeof(float);
        if (need <= ws_size) { C = cands[k]; break; }
    }
    if (C == 0) return;

    float* u_buf = ws;                            // C*9216
    float* regA  = ws + (size_t)C * 9216;         // C*184320
    float* h1    = regA;                          // C*102400
    float* part  = regA + (size_t)C * 102400;     // 4*C*9216 (disjoint from h1)
    float* uhat  = regA;                          // overwrites h1+part when both dead

    for (int b0 = 0; b0 < 512; b0 += C) {
        conv1_k<<<C * 16, 320, 0, stream>>>(input + (size_t)b0 * 784, c1w, c1b, h1);
        conv2_k<<<C * 4, 256, 0, stream>>>(h1, c2w, part, C);
        reduce_k<<<C * 9, 256, 0, stream>>>(part, c2b, u_buf, C);
        uhat_k<<<dim3(18, C / 8), 256, 0, stream>>>(u_buf, capW, uhat);
        route_k<<<C, 256, 0, stream>>>(uhat, out + (size_t)b0 * 160);
    }
}

// Round 4
// 4128.086 us; speedup vs baseline: 9.7212x; 9.7212x over previous
//
#include <hip/hip_runtime.h>
#include <hip/hip_bf16.h>

typedef __attribute__((ext_vector_type(8))) short bf16x8;
typedef __attribute__((ext_vector_type(4))) float f32x4;

static __device__ __forceinline__ unsigned short f2bf(float x) {
    __hip_bfloat16 h = __float2bfloat16(x);
    return *(unsigned short*)&h;
}

// ---------------- conv1 + ReLU: [512,1,28,28] -> h1n NHWC bf16 [512,20,20,256] ----------
// grid 512*16 blocks, 320 threads; block = (b, 16 c_out), thread = (co, oy) -> 20 ox outputs
__global__ __launch_bounds__(320) void conv1_k(const float* __restrict__ in,
                                               const float* __restrict__ w,
                                               const float* __restrict__ bias,
                                               unsigned short* __restrict__ h1n) {
    int blk = blockIdx.x;
    int b = blk >> 4;
    int c0 = (blk & 15) * 16;
    __shared__ float img[784];
    __shared__ float wl[16 * 81];
    __shared__ float bl[16];
    __shared__ unsigned short tr[20 * 328];   // [oy][ox*16+co], row stride 328 (pad)
    int tid = threadIdx.x;
    for (int t = tid; t < 784; t += 320) img[t] = in[b * 784 + t];
    for (int t = tid; t < 1296; t += 320) wl[t] = w[c0 * 81 + t];
    if (tid < 16) bl[tid] = bias[c0 + tid];
    __syncthreads();

    int co = tid / 20, oy = tid % 20;
    float wr[81];
#pragma unroll
    for (int k = 0; k < 81; k++) wr[k] = wl[co * 81 + k];
    float acc[20];
    float bv = bl[co];
#pragma unroll
    for (int ox = 0; ox < 20; ox++) acc[ox] = bv;

#pragma unroll
    for (int ky = 0; ky < 9; ky++) {
        const float* rp = &img[(oy + ky) * 28];
        float r[28];
#pragma unroll
        for (int v = 0; v < 7; v++) {
            float4 t4 = ((const float4*)rp)[v];
            r[v * 4 + 0] = t4.x; r[v * 4 + 1] = t4.y;
            r[v * 4 + 2] = t4.z; r[v * 4 + 3] = t4.w;
        }
#pragma unroll
        for (int kx = 0; kx < 9; kx++) {
            float wv = wr[ky * 9 + kx];
#pragma unroll
            for (int ox = 0; ox < 20; ox++) acc[ox] += r[ox + kx] * wv;
        }
    }
#pragma unroll
    for (int ox = 0; ox < 20; ox++)
        tr[oy * 328 + ox * 16 + co] = f2bf(fmaxf(acc[ox], 0.f));
    __syncthreads();
    // cooperative NHWC store: 400 pixels x 16 ch (this block's c0 slice) = 800 x 16B
    for (int g = tid; g < 800; g += 320) {
        int p = g >> 1, half = g & 1;
        uint4 v = *(uint4*)&tr[(p / 20) * 328 + (p % 20) * 16 + half * 8];
        *(uint4*)&h1n[(b * 400 + p) * 256 + c0 + half * 8] = v;
    }
}

// ---------------- W2 transpose: w2[cout][ci][ky][kx] fp32 -> Wt2[kk][cout][ci] bf16 -----
__global__ __launch_bounds__(256) void wt2_k(const float* __restrict__ w2,
                                             unsigned short* __restrict__ Wt2) {
    int cout = blockIdx.x;
    int ci = threadIdx.x;
    const float* src = w2 + (cout * 256 + ci) * 81;
#pragma unroll 1
    for (int kk = 0; kk < 81; kk++)
        Wt2[kk * 65536 + cout * 256 + ci] = f2bf(src[kk]);
}

// ---------------- conv2 as implicit GEMM, bf16 MFMA ----------------
// Out[R=b*36+oy*6+ox][cout] = sum_{kk,ci} h1n[b][2oy+ky][2ox+kx][ci] * Wt2[kk][cout][ci]
// Block tile 128x64, BK=64 (per kk: 4 rounds of 64 ci), 4 waves 2x2, wave tile 64x32.
__global__ __launch_bounds__(256) void conv2_k(const unsigned short* __restrict__ h1n,
                                               const unsigned short* __restrict__ Wt2,
                                               const float* __restrict__ bias,
                                               float* __restrict__ u) {
    __shared__ unsigned short sA[128 * 72];   // [row][64 ci] stride 72 (16B pad)
    __shared__ unsigned short sB[64 * 72];    // [cout][64 ci] stride 72
    int tid = threadIdx.x;
    int m0 = blockIdx.x * 128;
    int n0 = blockIdx.y * 64;

    // staging precompute: thread t -> A rows (t>>3)+{0,32,64,96}, 16B chunk c8=t&7
    int rl = tid >> 3;
    int c8 = tid & 7;
    int abase[4];
#pragma unroll
    for (int i = 0; i < 4; i++) {
        int R = m0 + rl + i * 32;
        int b = R / 36, m = R % 36;
        int oy = m / 6, ox = m % 6;
        abase[i] = b * 102400 + oy * 2 * 5120 + ox * 2 * 256 + c8 * 8;
    }
    int bbase0 = (n0 + rl) * 256 + c8 * 8;        // B rows rl and rl+32
    int bbase1 = (n0 + rl + 32) * 256 + c8 * 8;
    int aw = rl * 72 + c8 * 8;
    int bw = rl * 72 + c8 * 8;

    f32x4 acc[4][2];
#pragma unroll
    for (int i = 0; i < 4; i++)
#pragma unroll
        for (int j = 0; j < 2; j++) acc[i][j] = (f32x4){0.f, 0.f, 0.f, 0.f};

    int wv = tid >> 6, lane = tid & 63;
    int wm = wv >> 1, wn = wv & 1;
    int lr = lane & 15, quad = lane >> 4;

#pragma unroll 1
    for (int kk = 0; kk < 81; kk++) {
        int ky = kk / 9, kx = kk % 9;
        int aoff = ky * 5120 + kx * 256;
        int boff = kk * 65536;
#pragma unroll 1
        for (int cr = 0; cr < 4; cr++) {
            __syncthreads();
#pragma unroll
            for (int i = 0; i < 4; i++) {
                uint4 v = *(const uint4*)(h1n + abase[i] + aoff + cr * 64);
                *(uint4*)&sA[aw + i * 2304] = v;
            }
            {
                uint4 v0 = *(const uint4*)(Wt2 + boff + bbase0 + cr * 64);
                uint4 v1 = *(const uint4*)(Wt2 + boff + bbase1 + cr * 64);
                *(uint4*)&sB[bw] = v0;
                *(uint4*)&sB[bw + 2304] = v1;
            }
            __syncthreads();
#pragma unroll
            for (int s = 0; s < 2; s++) {
                bf16x8 bf[2];
#pragma unroll
                for (int j = 0; j < 2; j++)
                    bf[j] = *(bf16x8*)&sB[(wn * 32 + j * 16 + lr) * 72 + s * 32 + quad * 8];
#pragma unroll
                for (int i = 0; i < 4; i++) {
                    bf16x8 af = *(bf16x8*)&sA[(wm * 64 + i * 16 + lr) * 72 + s * 32 + quad * 8];
#pragma unroll
                    for (int j = 0; j < 2; j++)
                        acc[i][j] = __builtin_amdgcn_mfma_f32_16x16x32_bf16(
                            af, bf[j], acc[i][j], 0, 0, 0);
                }
            }
        }
    }
    // epilogue: C/D layout col=lane&15, row=quad*4+reg (m89-verified)
#pragma unroll
    for (int j = 0; j < 2; j++) {
        int col = n0 + wn * 32 + j * 16 + lr;
        float bv = bias[col];
#pragma unroll
        for (int i = 0; i < 4; i++) {
#pragma unroll
            for (int r = 0; r < 4; r++) {
                int R = m0 + wm * 64 + i * 16 + quad * 4 + r;
                int b = R / 36, m = R % 36;
                int oy = m / 6, ox = m % 6;
                u[b * 9216 + ox * 1536 + oy * 256 + col] = acc[i][j][r] + bv;
            }
        }
    }
}

// ---------------- u_hat: u[b,i,p] x W[i,j,p,q] -> uhat[b][j*16+q][i] ----------------
__global__ __launch_bounds__(256) void uhat_k(const float* __restrict__ u,
                                              const float* __restrict__ W,
                                              float* __restrict__ uhat) {
    int i0 = blockIdx.x * 64;
    int b0 = blockIdx.y * 8;
    __shared__ float ul[8 * 64 * 9];
    __shared__ float wl[64 * 129];
    int tid = threadIdx.x;

    for (int t = tid; t < 4096; t += 256) {
        int bb = t >> 9, r = t & 511;
        ul[bb * 576 + (r >> 3) * 9 + (r & 7)] = u[(b0 + bb) * 9216 + i0 * 8 + r];
    }

    int il = tid & 63, g = tid >> 6;
    for (int j = 0; j < 10; j++) {
        __syncthreads();
        for (int t = tid; t < 2048; t += 256) {
            int li = t >> 5, off = (t & 31) * 4;
            float4 v = *(const float4*)&W[(i0 + li) * 1280 + j * 128 + off];
            float* d = &wl[li * 129 + off];
            d[0] = v.x; d[1] = v.y; d[2] = v.z; d[3] = v.w;
        }
        __syncthreads();
#pragma unroll 1
        for (int bb = 0; bb < 8; bb++) {
            float ur[8];
#pragma unroll
            for (int p = 0; p < 8; p++) ur[p] = ul[bb * 576 + il * 9 + p];
#pragma unroll
            for (int k = 0; k < 4; k++) {
                int q = g * 4 + k;
                float a = 0.f;
#pragma unroll
                for (int p = 0; p < 8; p++) a += ur[p] * wl[il * 129 + p * 16 + q];
                uhat[((b0 + bb) * 160 + j * 16 + q) * 1152 + i0 + il] = a;
            }
        }
    }
}

// ---------------- dynamic routing (3 iters) -> out[Cr,10,16] ----------------
__global__ __launch_bounds__(256) void route_k(const float* __restrict__ uhat,
                                               float* __restrict__ out) {
    int b = blockIdx.x;
    int tid = threadIdx.x;
    __shared__ float c_lds[1152 * 10];
    __shared__ float s_lds[160];
    __shared__ float v_lds[160];
    const float* base = uhat + (size_t)b * 160 * 1152;

    float breg[5][10];
#pragma unroll
    for (int ch = 0; ch < 5; ch++)
#pragma unroll
        for (int j = 0; j < 10; j++) breg[ch][j] = 0.f;

    int wave = tid >> 6, lane = tid & 63;

    for (int t = 0; t < 3; t++) {
        if (t == 0) {
            for (int k = tid; k < 11520; k += 256) c_lds[k] = 0.1f;
        } else {
#pragma unroll
            for (int ch = 0; ch < 5; ch++) {
                int i = ch * 256 + tid;
                if (i < 1152) {
#pragma unroll
                    for (int j = 0; j < 10; j++) {
                        float d = 0.f;
#pragma unroll
                        for (int q = 0; q < 16; q++)
                            d += base[(j * 16 + q) * 1152 + i] * v_lds[j * 16 + q];
                        breg[ch][j] += d;
                    }
                    float m = breg[ch][0];
#pragma unroll
                    for (int j = 1; j < 10; j++) m = fmaxf(m, breg[ch][j]);
                    float e[10];
                    float sum = 0.f;
#pragma unroll
                    for (int j = 0; j < 10; j++) { e[j] = __expf(breg[ch][j] - m); sum += e[j]; }
                    float inv = 1.0f / sum;
#pragma unroll
                    for (int j = 0; j < 10; j++) c_lds[i * 10 + j] = e[j] * inv;
                }
            }
        }
        __syncthreads();
        for (int jq = wave; jq < 160; jq += 4) {
            int j = jq >> 4;
            const float* up = base + (size_t)jq * 1152;
            float s = 0.f;
#pragma unroll 2
            for (int k = 0; k < 18; k++) {
                int i = lane + k * 64;
                s += up[i] * c_lds[i * 10 + j];
            }
#pragma unroll
            for (int off = 32; off; off >>= 1) s += __shfl_down(s, off);
            if (lane == 0) s_lds[jq] = s;
        }
        __syncthreads();
        if (tid < 10) {
            float sq = 0.f;
#pragma unroll
            for (int q = 0; q < 16; q++) { float x = s_lds[tid * 16 + q]; sq += x * x; }
            float norm = sqrtf(sq + 1e-8f);
            float scale = (sq / (1.0f + sq)) / norm;
#pragma unroll
            for (int q = 0; q < 16; q++) v_lds[tid * 16 + q] = s_lds[tid * 16 + q] * scale;
        }
        __syncthreads();
    }
    if (tid < 160) out[b * 160 + tid] = v_lds[tid];
}

extern "C" void kernel_launch(void* const* d_in, const int* in_sizes, int n_in,
                              void* d_out, int out_size, void* d_ws, size_t ws_size,
                              hipStream_t stream) {
    const float* input = (const float*)d_in[0];
    const float* c1w = (const float*)d_in[1];
    const float* c1b = (const float*)d_in[2];
    const float* c2w = (const float*)d_in[3];
    const float* c2b = (const float*)d_in[4];
    const float* capW = (const float*)d_in[5];
    float* out = (float*)d_out;

    // ws layout (bytes):
    //   [0, 18874368)        u fp32 [512][9216]        (live until routing done)
    //   [18874368, ...)      region B:
    //        Wt2 bf16  10,616,832 B   } live during conv1/conv2
    //        h1n bf16 104,857,600 B   }
    //        uhat fp32 Cr*737280 B    overwrites Wt2+h1n after conv2
    const size_t U_BYTES = 18874368;
    const size_t WT2_BYTES = 10616832;
    const size_t H1N_BYTES = 104857600;
    if (ws_size < U_BYTES + WT2_BYTES + H1N_BYTES) return;

    float* u_buf = (float*)d_ws;
    char* regB = (char*)d_ws + U_BYTES;
    unsigned short* Wt2 = (unsigned short*)regB;
    unsigned short* h1n = (unsigned short*)(regB + WT2_BYTES);
    float* uhatb = (float*)regB;

    size_t availB = ws_size - U_BYTES;
    int Cr = 0;
    const int cands[7] = {512, 256, 128, 64, 32, 16, 8};
    for (int k = 0; k < 7; k++) {
        if ((size_t)cands[k] * 737280 <= availB) { Cr = cands[k]; break; }
    }
    if (Cr == 0) return;

    wt2_k<<<256, 256, 0, stream>>>(c2w, Wt2);
    conv1_k<<<512 * 16, 320, 0, stream>>>(input, c1w, c1b, h1n);
    conv2_k<<<dim3(144, 4), 256, 0, stream>>>(h1n, Wt2, c2b, u_buf);
    for (int b0 = 0; b0 < 512; b0 += Cr) {
        uhat_k<<<dim3(18, Cr / 8), 256, 0, stream>>>(u_buf + (size_t)b0 * 9216, capW, uhatb);
        route_k<<<Cr, 256, 0, stream>>>(uhatb, out + (size_t)b0 * 160);
    }
}

// Round 5
// 1261.993 us; speedup vs baseline: 31.7989x; 3.2711x over previous
//
#include <hip/hip_runtime.h>
#include <hip/hip_bf16.h>

typedef __attribute__((ext_vector_type(8))) short bf16x8;
typedef __attribute__((ext_vector_type(4))) float f32x4;

static __device__ __forceinline__ unsigned short f2bf(float x) {
    __hip_bfloat16 h = __float2bfloat16(x);
    return *(unsigned short*)&h;
}

// ---------------- conv1 + ReLU: [512,1,28,28] -> h1n NHWC bf16 [512,20,20,256] ----------
__global__ __launch_bounds__(320) void conv1_k(const float* __restrict__ in,
                                               const float* __restrict__ w,
                                               const float* __restrict__ bias,
                                               unsigned short* __restrict__ h1n) {
    int blk = blockIdx.x;
    int b = blk >> 4;
    int c0 = (blk & 15) * 16;
    __shared__ float img[784];
    __shared__ float wl[16 * 81];
    __shared__ float bl[16];
    __shared__ unsigned short tr[20 * 328];
    int tid = threadIdx.x;
    for (int t = tid; t < 784; t += 320) img[t] = in[b * 784 + t];
    for (int t = tid; t < 1296; t += 320) wl[t] = w[c0 * 81 + t];
    if (tid < 16) bl[tid] = bias[c0 + tid];
    __syncthreads();

    int co = tid / 20, oy = tid % 20;
    float wr[81];
#pragma unroll
    for (int k = 0; k < 81; k++) wr[k] = wl[co * 81 + k];
    float acc[20];
    float bv = bl[co];
#pragma unroll
    for (int ox = 0; ox < 20; ox++) acc[ox] = bv;

#pragma unroll
    for (int ky = 0; ky < 9; ky++) {
        const float* rp = &img[(oy + ky) * 28];
        float r[28];
#pragma unroll
        for (int v = 0; v < 7; v++) {
            float4 t4 = ((const float4*)rp)[v];
            r[v * 4 + 0] = t4.x; r[v * 4 + 1] = t4.y;
            r[v * 4 + 2] = t4.z; r[v * 4 + 3] = t4.w;
        }
#pragma unroll
        for (int kx = 0; kx < 9; kx++) {
            float wv = wr[ky * 9 + kx];
#pragma unroll
            for (int ox = 0; ox < 20; ox++) acc[ox] += r[ox + kx] * wv;
        }
    }
#pragma unroll
    for (int ox = 0; ox < 20; ox++)
        tr[oy * 328 + ox * 16 + co] = f2bf(fmaxf(acc[ox], 0.f));
    __syncthreads();
    for (int g = tid; g < 800; g += 320) {
        int p = g >> 1, half = g & 1;
        uint4 v = *(uint4*)&tr[(p / 20) * 328 + (p % 20) * 16 + half * 8];
        *(uint4*)&h1n[(b * 400 + p) * 256 + c0 + half * 8] = v;
    }
}

// ---------------- W2 transpose: w2[cout][ci][kk] fp32 -> Wt2[kk][cout][ci] bf16 -----
__global__ __launch_bounds__(256) void wt2_k(const float* __restrict__ w2,
                                             unsigned short* __restrict__ Wt2) {
    int cout = blockIdx.x;
    int ci = threadIdx.x;
    const float* src = w2 + (cout * 256 + ci) * 81;
#pragma unroll 1
    for (int kk = 0; kk < 81; kk++)
        Wt2[kk * 65536 + cout * 256 + ci] = f2bf(src[kk]);
}

// ---------------- conv2 as implicit GEMM, bf16 MFMA (unchanged, verified R4) ------------
__global__ __launch_bounds__(256) void conv2_k(const unsigned short* __restrict__ h1n,
                                               const unsigned short* __restrict__ Wt2,
                                               const float* __restrict__ bias,
                                               float* __restrict__ u) {
    __shared__ unsigned short sA[128 * 72];
    __shared__ unsigned short sB[64 * 72];
    int tid = threadIdx.x;
    int m0 = blockIdx.x * 128;
    int n0 = blockIdx.y * 64;

    int rl = tid >> 3;
    int c8 = tid & 7;
    int abase[4];
#pragma unroll
    for (int i = 0; i < 4; i++) {
        int R = m0 + rl + i * 32;
        int b = R / 36, m = R % 36;
        int oy = m / 6, ox = m % 6;
        abase[i] = b * 102400 + oy * 2 * 5120 + ox * 2 * 256 + c8 * 8;
    }
    int bbase0 = (n0 + rl) * 256 + c8 * 8;
    int bbase1 = (n0 + rl + 32) * 256 + c8 * 8;
    int aw = rl * 72 + c8 * 8;
    int bw = rl * 72 + c8 * 8;

    f32x4 acc[4][2];
#pragma unroll
    for (int i = 0; i < 4; i++)
#pragma unroll
        for (int j = 0; j < 2; j++) acc[i][j] = (f32x4){0.f, 0.f, 0.f, 0.f};

    int wv = tid >> 6, lane = tid & 63;
    int wm = wv >> 1, wn = wv & 1;
    int lr = lane & 15, quad = lane >> 4;

#pragma unroll 1
    for (int kk = 0; kk < 81; kk++) {
        int ky = kk / 9, kx = kk % 9;
        int aoff = ky * 5120 + kx * 256;
        int boff = kk * 65536;
#pragma unroll 1
        for (int cr = 0; cr < 4; cr++) {
            __syncthreads();
#pragma unroll
            for (int i = 0; i < 4; i++) {
                uint4 v = *(const uint4*)(h1n + abase[i] + aoff + cr * 64);
                *(uint4*)&sA[aw + i * 2304] = v;
            }
            {
                uint4 v0 = *(const uint4*)(Wt2 + boff + bbase0 + cr * 64);
                uint4 v1 = *(const uint4*)(Wt2 + boff + bbase1 + cr * 64);
                *(uint4*)&sB[bw] = v0;
                *(uint4*)&sB[bw + 2304] = v1;
            }
            __syncthreads();
#pragma unroll
            for (int s = 0; s < 2; s++) {
                bf16x8 bf[2];
#pragma unroll
                for (int j = 0; j < 2; j++)
                    bf[j] = *(bf16x8*)&sB[(wn * 32 + j * 16 + lr) * 72 + s * 32 + quad * 8];
#pragma unroll
                for (int i = 0; i < 4; i++) {
                    bf16x8 af = *(bf16x8*)&sA[(wm * 64 + i * 16 + lr) * 72 + s * 32 + quad * 8];
#pragma unroll
                    for (int j = 0; j < 2; j++)
                        acc[i][j] = __builtin_amdgcn_mfma_f32_16x16x32_bf16(
                            af, bf[j], acc[i][j], 0, 0, 0);
                }
            }
        }
    }
#pragma unroll
    for (int j = 0; j < 2; j++) {
        int col = n0 + wn * 32 + j * 16 + lr;
        float bv = bias[col];
#pragma unroll
        for (int i = 0; i < 4; i++) {
#pragma unroll
            for (int r = 0; r < 4; r++) {
                int R = m0 + wm * 64 + i * 16 + quad * 4 + r;
                int b = R / 36, m = R % 36;
                int oy = m / 6, ox = m % 6;
                u[b * 9216 + ox * 1536 + oy * 256 + col] = acc[i][j][r] + bv;
            }
        }
    }
}

// ---------------- u_hat: u[b,i,p] x W[i,j,p,q] -> uhat bf16 [b][j*16+q][i] ----------------
__global__ __launch_bounds__(256) void uhat_k(const float* __restrict__ u,
                                              const float* __restrict__ W,
                                              unsigned short* __restrict__ uhat) {
    int i0 = blockIdx.x * 64;
    int b0 = blockIdx.y * 8;
    __shared__ float ul[8 * 64 * 9];
    __shared__ float wl[64 * 129];
    int tid = threadIdx.x;

    for (int t = tid; t < 4096; t += 256) {
        int bb = t >> 9, r = t & 511;
        ul[bb * 576 + (r >> 3) * 9 + (r & 7)] = u[(b0 + bb) * 9216 + i0 * 8 + r];
    }

    int il = tid & 63, g = tid >> 6;
    for (int j = 0; j < 10; j++) {
        __syncthreads();
        for (int t = tid; t < 2048; t += 256) {
            int li = t >> 5, off = (t & 31) * 4;
            float4 v = *(const float4*)&W[(i0 + li) * 1280 + j * 128 + off];
            float* d = &wl[li * 129 + off];
            d[0] = v.x; d[1] = v.y; d[2] = v.z; d[3] = v.w;
        }
        __syncthreads();
#pragma unroll 1
        for (int bb = 0; bb < 8; bb++) {
            float ur[8];
#pragma unroll
            for (int p = 0; p < 8; p++) ur[p] = ul[bb * 576 + il * 9 + p];
#pragma unroll
            for (int k = 0; k < 4; k++) {
                int q = g * 4 + k;
                float a = 0.f;
#pragma unroll
                for (int p = 0; p < 8; p++) a += ur[p] * wl[il * 129 + p * 16 + q];
                uhat[((size_t)(b0 + bb) * 160 + j * 16 + q) * 1152 + i0 + il] = f2bf(a);
            }
        }
    }
}

// ---------------- dynamic routing (3 iters) -> out[Cr,10,16] ----------------
// 576 threads (9 waves) per block, one block per b. Thread = 2 capsules (i=2t,2t+1).
__global__ __launch_bounds__(576) void route_k(const unsigned short* __restrict__ uhat,
                                               float* __restrict__ out) {
    int b = blockIdx.x;
    int tid = threadIdx.x;
    int wave = tid >> 6, lane = tid & 63;
    __shared__ float c_lds[10 * 1152];   // [j][i] — transposed: conflict-free, float4-able
    __shared__ float s_lds[160];
    __shared__ float v_lds[160];
    const unsigned short* base = uhat + (size_t)b * 184320;

    float b0[10], b1[10];
#pragma unroll
    for (int j = 0; j < 10; j++) { b0[j] = 0.f; b1[j] = 0.f; }

    for (int t = 0; t < 3; t++) {
        if (t > 0) {
            // ---- phase A: logits += dot(uhat_i, v); softmax -> c (for i=2t, 2t+1) ----
#pragma unroll
            for (int j = 0; j < 10; j++) {
                float a0 = 0.f, a1 = 0.f;
#pragma unroll
                for (int q = 0; q < 16; q++) {
                    unsigned int w = *(const unsigned int*)(base + (j * 16 + q) * 1152 + 2 * tid);
                    float x0 = __uint_as_float(w << 16);
                    float x1 = __uint_as_float(w & 0xffff0000u);
                    float vv = v_lds[j * 16 + q];
                    a0 = fmaf(x0, vv, a0);
                    a1 = fmaf(x1, vv, a1);
                }
                b0[j] += a0; b1[j] += a1;
            }
            float m0 = b0[0], m1 = b1[0];
#pragma unroll
            for (int j = 1; j < 10; j++) { m0 = fmaxf(m0, b0[j]); m1 = fmaxf(m1, b1[j]); }
            float e0[10], e1[10], sum0 = 0.f, sum1 = 0.f;
#pragma unroll
            for (int j = 0; j < 10; j++) {
                e0[j] = __expf(b0[j] - m0); sum0 += e0[j];
                e1[j] = __expf(b1[j] - m1); sum1 += e1[j];
            }
            float inv0 = 1.f / sum0, inv1 = 1.f / sum1;
#pragma unroll
            for (int j = 0; j < 10; j++) {
                float2 cc; cc.x = e0[j] * inv0; cc.y = e1[j] * inv1;
                *(float2*)&c_lds[j * 1152 + 2 * tid] = cc;
            }
        }
        __syncthreads();
        // ---- phase B: s_row = sum_i c[j][i] * uhat[row][i], wave-per-row ----
        for (int row = wave; row < 160; row += 9) {
            int j = row >> 4;
            const unsigned short* up = base + row * 1152;
            float s = 0.f;
            if (t == 0) {
#pragma unroll
                for (int r = 0; r < 3; r++) {
                    int ch = r * 64 + lane;
                    if (ch < 144) {
                        bf16x8 uv = *(const bf16x8*)(up + ch * 8);
#pragma unroll
                        for (int m = 0; m < 8; m++)
                            s += __uint_as_float(((unsigned int)(unsigned short)uv[m]) << 16);
                    }
                }
                s *= 0.1f;
            } else {
                const float* cp = &c_lds[j * 1152];
#pragma unroll
                for (int r = 0; r < 3; r++) {
                    int ch = r * 64 + lane;
                    if (ch < 144) {
                        bf16x8 uv = *(const bf16x8*)(up + ch * 8);
                        float4 ca = *(const float4*)&cp[ch * 8];
                        float4 cb = *(const float4*)&cp[ch * 8 + 4];
                        s = fmaf(__uint_as_float(((unsigned int)(unsigned short)uv[0]) << 16), ca.x, s);
                        s = fmaf(__uint_as_float(((unsigned int)(unsigned short)uv[1]) << 16), ca.y, s);
                        s = fmaf(__uint_as_float(((unsigned int)(unsigned short)uv[2]) << 16), ca.z, s);
                        s = fmaf(__uint_as_float(((unsigned int)(unsigned short)uv[3]) << 16), ca.w, s);
                        s = fmaf(__uint_as_float(((unsigned int)(unsigned short)uv[4]) << 16), cb.x, s);
                        s = fmaf(__uint_as_float(((unsigned int)(unsigned short)uv[5]) << 16), cb.y, s);
                        s = fmaf(__uint_as_float(((unsigned int)(unsigned short)uv[6]) << 16), cb.z, s);
                        s = fmaf(__uint_as_float(((unsigned int)(unsigned short)uv[7]) << 16), cb.w, s);
                    }
                }
            }
#pragma unroll
            for (int off = 32; off; off >>= 1) s += __shfl_down(s, off);
            if (lane == 0) s_lds[row] = s;
        }
        __syncthreads();
        // ---- squash ----
        if (tid < 10) {
            float sq = 0.f;
#pragma unroll
            for (int q = 0; q < 16; q++) { float x = s_lds[tid * 16 + q]; sq += x * x; }
            float norm = sqrtf(sq + 1e-8f);
            float scale = (sq / (1.0f + sq)) / norm;
#pragma unroll
            for (int q = 0; q < 16; q++) v_lds[tid * 16 + q] = s_lds[tid * 16 + q] * scale;
        }
        __syncthreads();
    }
    if (tid < 160) out[b * 160 + tid] = v_lds[tid];
}

extern "C" void kernel_launch(void* const* d_in, const int* in_sizes, int n_in,
                              void* d_out, int out_size, void* d_ws, size_t ws_size,
                              hipStream_t stream) {
    const float* input = (const float*)d_in[0];
    const float* c1w = (const float*)d_in[1];
    const float* c1b = (const float*)d_in[2];
    const float* c2w = (const float*)d_in[3];
    const float* c2b = (const float*)d_in[4];
    const float* capW = (const float*)d_in[5];
    float* out = (float*)d_out;

    // ws: [0, U) u fp32 [512][9216]; region B: {Wt2 bf16 + h1n bf16} then uhat bf16 reuse.
    const size_t U_BYTES = 18874368;
    const size_t WT2_BYTES = 10616832;
    const size_t H1N_BYTES = 104857600;
    if (ws_size < U_BYTES + WT2_BYTES + H1N_BYTES) return;

    float* u_buf = (float*)d_ws;
    char* regB = (char*)d_ws + U_BYTES;
    unsigned short* Wt2 = (unsigned short*)regB;
    unsigned short* h1n = (unsigned short*)(regB + WT2_BYTES);
    unsigned short* uhatb = (unsigned short*)regB;

    size_t availB = ws_size - U_BYTES;
    int Cr = 0;
    const int cands[7] = {512, 256, 128, 64, 32, 16, 8};
    for (int k = 0; k < 7; k++) {
        if ((size_t)cands[k] * 368640 <= availB) { Cr = cands[k]; break; }
    }
    if (Cr == 0) return;  // availB >= 115.5 MB guarantees Cr >= 256 in practice

    wt2_k<<<256, 256, 0, stream>>>(c2w, Wt2);
    conv1_k<<<512 * 16, 320, 0, stream>>>(input, c1w, c1b, h1n);
    conv2_k<<<dim3(144, 4), 256, 0, stream>>>(h1n, Wt2, c2b, u_buf);
    for (int b0 = 0; b0 < 512; b0 += Cr) {
        uhat_k<<<dim3(18, Cr / 8), 256, 0, stream>>>(u_buf + (size_t)b0 * 9216, capW, uhatb);
        route_k<<<Cr, 576, 0, stream>>>(uhatb, out + (size_t)b0 * 160);
    }
}

// Round 6
// 1038.447 us; speedup vs baseline: 38.6442x; 1.2153x over previous
//
#include <hip/hip_runtime.h>
#include <hip/hip_bf16.h>

typedef __attribute__((ext_vector_type(8))) short bf16x8;
typedef __attribute__((ext_vector_type(4))) float f32x4;

static __device__ __forceinline__ unsigned short f2bf(float x) {
    __hip_bfloat16 h = __float2bfloat16(x);
    return *(unsigned short*)&h;
}
static __device__ __forceinline__ float bflo(unsigned int w) { return __uint_as_float(w << 16); }
static __device__ __forceinline__ float bfhi(unsigned int w) { return __uint_as_float(w & 0xffff0000u); }
static __device__ __forceinline__ float bf1(unsigned short u) { return __uint_as_float(((unsigned int)u) << 16); }

// ---------------- conv1 + ReLU: [512,1,28,28] -> h1n NHWC bf16 [512,20,20,256] ----------
__global__ __launch_bounds__(320) void conv1_k(const float* __restrict__ in,
                                               const float* __restrict__ w,
                                               const float* __restrict__ bias,
                                               unsigned short* __restrict__ h1n) {
    int blk = blockIdx.x;
    int b = blk >> 4;
    int c0 = (blk & 15) * 16;
    __shared__ float img[784];
    __shared__ float wl[16 * 81];
    __shared__ float bl[16];
    __shared__ unsigned short tr[20 * 328];
    int tid = threadIdx.x;
    for (int t = tid; t < 784; t += 320) img[t] = in[b * 784 + t];
    for (int t = tid; t < 1296; t += 320) wl[t] = w[c0 * 81 + t];
    if (tid < 16) bl[tid] = bias[c0 + tid];
    __syncthreads();

    int co = tid / 20, oy = tid % 20;
    float wr[81];
#pragma unroll
    for (int k = 0; k < 81; k++) wr[k] = wl[co * 81 + k];
    float acc[20];
    float bv = bl[co];
#pragma unroll
    for (int ox = 0; ox < 20; ox++) acc[ox] = bv;

#pragma unroll
    for (int ky = 0; ky < 9; ky++) {
        const float* rp = &img[(oy + ky) * 28];
        float r[28];
#pragma unroll
        for (int v = 0; v < 7; v++) {
            float4 t4 = ((const float4*)rp)[v];
            r[v * 4 + 0] = t4.x; r[v * 4 + 1] = t4.y;
            r[v * 4 + 2] = t4.z; r[v * 4 + 3] = t4.w;
        }
#pragma unroll
        for (int kx = 0; kx < 9; kx++) {
            float wv = wr[ky * 9 + kx];
#pragma unroll
            for (int ox = 0; ox < 20; ox++) acc[ox] += r[ox + kx] * wv;
        }
    }
#pragma unroll
    for (int ox = 0; ox < 20; ox++)
        tr[oy * 328 + ox * 16 + co] = f2bf(fmaxf(acc[ox], 0.f));
    __syncthreads();
    for (int g = tid; g < 800; g += 320) {
        int p = g >> 1, half = g & 1;
        uint4 v = *(uint4*)&tr[(p / 20) * 328 + (p % 20) * 16 + half * 8];
        *(uint4*)&h1n[(b * 400 + p) * 256 + c0 + half * 8] = v;
    }
}

// ---------------- W2 transpose -----------------------------------------------------------
__global__ __launch_bounds__(256) void wt2_k(const float* __restrict__ w2,
                                             unsigned short* __restrict__ Wt2) {
    int cout = blockIdx.x;
    int ci = threadIdx.x;
    const float* src = w2 + (cout * 256 + ci) * 81;
#pragma unroll 1
    for (int kk = 0; kk < 81; kk++)
        Wt2[kk * 65536 + cout * 256 + ci] = f2bf(src[kk]);
}

// ---------------- conv2 implicit GEMM, bf16 MFMA (verified R4) ---------------------------
__global__ __launch_bounds__(256) void conv2_k(const unsigned short* __restrict__ h1n,
                                               const unsigned short* __restrict__ Wt2,
                                               const float* __restrict__ bias,
                                               float* __restrict__ u) {
    __shared__ unsigned short sA[128 * 72];
    __shared__ unsigned short sB[64 * 72];
    int tid = threadIdx.x;
    int m0 = blockIdx.x * 128;
    int n0 = blockIdx.y * 64;

    int rl = tid >> 3;
    int c8 = tid & 7;
    int abase[4];
#pragma unroll
    for (int i = 0; i < 4; i++) {
        int R = m0 + rl + i * 32;
        int b = R / 36, m = R % 36;
        int oy = m / 6, ox = m % 6;
        abase[i] = b * 102400 + oy * 2 * 5120 + ox * 2 * 256 + c8 * 8;
    }
    int bbase0 = (n0 + rl) * 256 + c8 * 8;
    int bbase1 = (n0 + rl + 32) * 256 + c8 * 8;
    int aw = rl * 72 + c8 * 8;
    int bw = rl * 72 + c8 * 8;

    f32x4 acc[4][2];
#pragma unroll
    for (int i = 0; i < 4; i++)
#pragma unroll
        for (int j = 0; j < 2; j++) acc[i][j] = (f32x4){0.f, 0.f, 0.f, 0.f};

    int wv = tid >> 6, lane = tid & 63;
    int wm = wv >> 1, wn = wv & 1;
    int lr = lane & 15, quad = lane >> 4;

#pragma unroll 1
    for (int kk = 0; kk < 81; kk++) {
        int ky = kk / 9, kx = kk % 9;
        int aoff = ky * 5120 + kx * 256;
        int boff = kk * 65536;
#pragma unroll 1
        for (int cr = 0; cr < 4; cr++) {
            __syncthreads();
#pragma unroll
            for (int i = 0; i < 4; i++) {
                uint4 v = *(const uint4*)(h1n + abase[i] + aoff + cr * 64);
                *(uint4*)&sA[aw + i * 2304] = v;
            }
            {
                uint4 v0 = *(const uint4*)(Wt2 + boff + bbase0 + cr * 64);
                uint4 v1 = *(const uint4*)(Wt2 + boff + bbase1 + cr * 64);
                *(uint4*)&sB[bw] = v0;
                *(uint4*)&sB[bw + 2304] = v1;
            }
            __syncthreads();
#pragma unroll
            for (int s = 0; s < 2; s++) {
                bf16x8 bf[2];
#pragma unroll
                for (int j = 0; j < 2; j++)
                    bf[j] = *(bf16x8*)&sB[(wn * 32 + j * 16 + lr) * 72 + s * 32 + quad * 8];
#pragma unroll
                for (int i = 0; i < 4; i++) {
                    bf16x8 af = *(bf16x8*)&sA[(wm * 64 + i * 16 + lr) * 72 + s * 32 + quad * 8];
#pragma unroll
                    for (int j = 0; j < 2; j++)
                        acc[i][j] = __builtin_amdgcn_mfma_f32_16x16x32_bf16(
                            af, bf[j], acc[i][j], 0, 0, 0);
                }
            }
        }
    }
#pragma unroll
    for (int j = 0; j < 2; j++) {
        int col = n0 + wn * 32 + j * 16 + lr;
        float bv = bias[col];
#pragma unroll
        for (int i = 0; i < 4; i++) {
#pragma unroll
            for (int r = 0; r < 4; r++) {
                int R = m0 + wm * 64 + i * 16 + quad * 4 + r;
                int b = R / 36, m = R % 36;
                int oy = m / 6, ox = m % 6;
                u[b * 9216 + ox * 1536 + oy * 256 + col] = acc[i][j][r] + bv;
            }
        }
    }
}

// ---------------- u_hat: u[b,i,p] x W[i,j,p,q] -> uhat bf16 [b][j*16+q][i] ---------------
__global__ __launch_bounds__(256) void uhat_k(const float* __restrict__ u,
                                              const float* __restrict__ W,
                                              unsigned short* __restrict__ uhat) {
    int i0 = blockIdx.x * 64;
    int b0 = blockIdx.y * 8;
    __shared__ float ul[8 * 64 * 9];
    __shared__ float wl[64 * 129];
    int tid = threadIdx.x;

    for (int t = tid; t < 4096; t += 256) {
        int bb = t >> 9, r = t & 511;
        ul[bb * 576 + (r >> 3) * 9 + (r & 7)] = u[(b0 + bb) * 9216 + i0 * 8 + r];
    }

    int il = tid & 63, g = tid >> 6;
    for (int j = 0; j < 10; j++) {
        __syncthreads();
        for (int t = tid; t < 2048; t += 256) {
            int li = t >> 5, off = (t & 31) * 4;
            float4 v = *(const float4*)&W[(i0 + li) * 1280 + j * 128 + off];
            float* d = &wl[li * 129 + off];
            d[0] = v.x; d[1] = v.y; d[2] = v.z; d[3] = v.w;
        }
        __syncthreads();
#pragma unroll 1
        for (int bb = 0; bb < 8; bb++) {
            float ur[8];
#pragma unroll
            for (int p = 0; p < 8; p++) ur[p] = ul[bb * 576 + il * 9 + p];
#pragma unroll
            for (int k = 0; k < 4; k++) {
                int q = g * 4 + k;
                float a = 0.f;
#pragma unroll
                for (int p = 0; p < 8; p++) a += ur[p] * wl[il * 129 + p * 16 + q];
                uhat[((size_t)(b0 + bb) * 160 + j * 16 + q) * 1152 + i0 + il] = f2bf(a);
            }
        }
    }
}

// ---------------- zero s buffer ----------------------------------------------------------
__global__ __launch_bounds__(256) void zero_k(float* __restrict__ p, int n) {
    int k = blockIdx.x * 256 + threadIdx.x;
    if (k < n) p[k] = 0.f;
}

// ---------------- fused routing iteration: logits-update + softmax + partial-s -----------
// grid (9 i-chunks, Cr b), 256 threads. One pass over uhat per iteration.
// MODE 0: t=0 (c=0.1, no phase A). MODE 1: t=1 (logits = dot, write). MODE 2: t=2 (read+update).
template <int MODE>
__global__ __launch_bounds__(256) void routeAB_k(const unsigned short* __restrict__ uhat,
                                                 const float* __restrict__ v_in,
                                                 float* __restrict__ logits,
                                                 float* __restrict__ s_glob) {
    int chunk = blockIdx.x;     // 0..8 -> i0 = chunk*128
    int b = blockIdx.y;
    int tid = threadIdx.x;
    __shared__ unsigned short su[160 * 128];   // [jq][il] bf16, 40960 B
    __shared__ float c_sh[10 * 128];
    __shared__ float v_sh[160];
    const unsigned short* base = uhat + (size_t)b * 184320 + chunk * 128;

    // stage 160 rows x 128 bf16 (16 threads/row, 16B each)
#pragma unroll
    for (int rnd = 0; rnd < 10; rnd++) {
        int idx = rnd * 256 + tid;
        int row = idx >> 4, c16 = idx & 15;
        uint4 vv = *(const uint4*)(base + row * 1152 + c16 * 8);
        *(uint4*)&su[row * 128 + c16 * 8] = vv;
    }
    if (MODE > 0 && tid < 160) v_sh[tid] = v_in[b * 160 + tid];
    __syncthreads();

    if (MODE > 0) {
        int i = tid >> 1, h = tid & 1;   // thread pair shares capsule i; h = row-half
        int gi = chunk * 128 + i;
        // accumulate dot(uhat_i, v) over this half's 5 j's
        float la[5];
#pragma unroll
        for (int jj = 0; jj < 5; jj++) {
            float a = 0.f;
            int jbase = (h * 5 + jj) * 16;
#pragma unroll
            for (int q = 0; q < 16; q++)
                a = fmaf(bf1(su[(jbase + q) * 128 + i]), v_sh[jbase + q], a);
            la[jj] = a;
        }
        float lg[10];
#pragma unroll
        for (int j = 0; j < 10; j++) {
            float contrib = ((j / 5) == h) ? la[j % 5] : 0.f;
            contrib += __shfl_xor(contrib, 1);
            if (MODE == 2) contrib += logits[(size_t)b * 11520 + j * 1152 + gi];
            lg[j] = contrib;
        }
        if (MODE == 1 && h == 0) {
            float* lp = logits + (size_t)b * 11520 + gi;
#pragma unroll
            for (int j = 0; j < 10; j++) lp[j * 1152] = lg[j];
        }
        // softmax over j
        float m = lg[0];
#pragma unroll
        for (int j = 1; j < 10; j++) m = fmaxf(m, lg[j]);
        float e[10], sum = 0.f;
#pragma unroll
        for (int j = 0; j < 10; j++) { e[j] = __expf(lg[j] - m); sum += e[j]; }
        float inv = 1.f / sum;
        if (h == 0) {
#pragma unroll
            for (int j = 0; j < 10; j++) c_sh[j * 128 + i] = e[j] * inv;
        }
    }
    __syncthreads();

    // phase B: partial s over this chunk's 128 i's; wave-per-row
    int wv = tid >> 6, lane = tid & 63;
#pragma unroll 1
    for (int row = wv; row < 160; row += 4) {
        unsigned int uv = *(const unsigned int*)&su[row * 128 + lane * 2];
        float x0 = bflo(uv), x1 = bfhi(uv);
        float p;
        if (MODE == 0) {
            p = (x0 + x1) * 0.1f;
        } else {
            int j = row >> 4;
            float2 cc = *(const float2*)&c_sh[j * 128 + lane * 2];
            p = fmaf(x0, cc.x, x1 * cc.y);
        }
#pragma unroll
        for (int off = 32; off; off >>= 1) p += __shfl_down(p, off);
        if (lane == 0) atomicAdd(&s_glob[b * 160 + row], p);
    }
}

// ---------------- squash: s -> v (or out), re-zero s -------------------------------------
template <int LAST>
__global__ __launch_bounds__(192) void squash_k(float* __restrict__ s_glob,
                                                float* __restrict__ v_glob,
                                                float* __restrict__ out) {
    int b = blockIdx.x, tid = threadIdx.x;
    __shared__ float s_sh[160];
    __shared__ float sc[10];
    if (tid < 160) s_sh[tid] = s_glob[b * 160 + tid];
    __syncthreads();
    if (tid < 10) {
        float sq = 0.f;
#pragma unroll
        for (int q = 0; q < 16; q++) { float x = s_sh[tid * 16 + q]; sq += x * x; }
        float norm = sqrtf(sq + 1e-8f);
        sc[tid] = (sq / (1.0f + sq)) / norm;
    }
    __syncthreads();
    if (tid < 160) {
        float v = s_sh[tid] * sc[tid >> 4];
        if (LAST) out[b * 160 + tid] = v;
        else v_glob[b * 160 + tid] = v;
        s_glob[b * 160 + tid] = 0.f;   // clean for next iteration
    }
}

extern "C" void kernel_launch(void* const* d_in, const int* in_sizes, int n_in,
                              void* d_out, int out_size, void* d_ws, size_t ws_size,
                              hipStream_t stream) {
    const float* input = (const float*)d_in[0];
    const float* c1w = (const float*)d_in[1];
    const float* c1b = (const float*)d_in[2];
    const float* c2w = (const float*)d_in[3];
    const float* c2b = (const float*)d_in[4];
    const float* capW = (const float*)d_in[5];
    float* out = (float*)d_out;

    // ws layout (bytes):
    //   [0)            u fp32 [512][9216]                      18,874,368
    //   [+18874368)    s_glob fp32 [512][160]                     327,680
    //   [+19202048)    v_glob fp32 [512][160]                     327,680
    //   [+19529728)    logits fp32 [<=512][10][1152]           23,592,960
    //   [+43122688)    region B: {Wt2 + h1n} (conv, 115.5 MB) then uhat bf16 (Cr*368640)
    const size_t U_OFF = 0;
    const size_t S_OFF = 18874368;
    const size_t V_OFF = 19202048;
    const size_t L_OFF = 19529728;
    const size_t B_OFF = 43122688;
    const size_t CONV_BYTES = 10616832 + 104857600;
    if (ws_size < B_OFF + CONV_BYTES) return;

    char* wsb = (char*)d_ws;
    float* u_buf = (float*)(wsb + U_OFF);
    float* s_glob = (float*)(wsb + S_OFF);
    float* v_glob = (float*)(wsb + V_OFF);
    float* logits = (float*)(wsb + L_OFF);
    unsigned short* Wt2 = (unsigned short*)(wsb + B_OFF);
    unsigned short* h1n = (unsigned short*)(wsb + B_OFF + 10616832);
    unsigned short* uhatb = (unsigned short*)(wsb + B_OFF);

    size_t availB = ws_size - B_OFF;
    int Cr = 0;
    const int cands[7] = {512, 256, 128, 64, 32, 16, 8};
    for (int k = 0; k < 7; k++) {
        if ((size_t)cands[k] * 368640 <= availB) { Cr = cands[k]; break; }
    }
    if (Cr == 0) return;

    zero_k<<<320, 256, 0, stream>>>(s_glob, 81920);
    wt2_k<<<256, 256, 0, stream>>>(c2w, Wt2);
    conv1_k<<<512 * 16, 320, 0, stream>>>(input, c1w, c1b, h1n);
    conv2_k<<<dim3(144, 4), 256, 0, stream>>>(h1n, Wt2, c2b, u_buf);

    for (int b0 = 0; b0 < 512; b0 += Cr) {
        uhat_k<<<dim3(18, Cr / 8), 256, 0, stream>>>(u_buf + (size_t)b0 * 9216, capW, uhatb);
        routeAB_k<0><<<dim3(9, Cr), 256, 0, stream>>>(uhatb, v_glob, logits, s_glob);
        squash_k<0><<<Cr, 192, 0, stream>>>(s_glob, v_glob, out);
        routeAB_k<1><<<dim3(9, Cr), 256, 0, stream>>>(uhatb, v_glob, logits, s_glob);
        squash_k<0><<<Cr, 192, 0, stream>>>(s_glob, v_glob, out);
        routeAB_k<2><<<dim3(9, Cr), 256, 0, stream>>>(uhatb, v_glob, logits, s_glob);
        squash_k<1><<<Cr, 192, 0, stream>>>(s_glob, v_glob, out + (size_t)b0 * 160);
    }
}